// Round 5
// baseline (301.294 us; speedup 1.0000x reference)
//
#include <hip/hip_runtime.h>

// Flash attention fwd: fp32 I/O, bf16 MFMA, fp32 softmax math.
// BH=32, S=2048, D=64, additive mask [2,S,S] tiled bh%2.
// R5: software-pipelined tiles — PV deferred one tile (sP dbuf, sV 3-ring),
// mask prefetched one tile ahead, single barrier/tile, XOR-swizzled LDS.

constexpr int cBH = 32;
constexpr int cS  = 2048;
constexpr int cD  = 64;
constexpr int cQT = 128;            // 8 waves x 16 q-rows
constexpr int cNT = cS / 64;        // 32 k-tiles

typedef __bf16 bf16x8 __attribute__((ext_vector_type(8)));
typedef __bf16 bf16x4 __attribute__((ext_vector_type(4)));
typedef float  f32x4  __attribute__((ext_vector_type(4)));

__device__ __forceinline__ unsigned short bfbits(float f) {
    return __builtin_bit_cast(unsigned short, (__bf16)f);
}
__device__ __forceinline__ bf16x4 pack4(f32x4 a) {
    bf16x4 r;
    r[0] = (__bf16)a[0]; r[1] = (__bf16)a[1];
    r[2] = (__bf16)a[2]; r[3] = (__bf16)a[3];
    return r;
}
__device__ __forceinline__ bf16x8 pack8s(f32x4 a, f32x4 b, float s) {
    bf16x8 r;
    r[0] = (__bf16)(a[0]*s); r[1] = (__bf16)(a[1]*s);
    r[2] = (__bf16)(a[2]*s); r[3] = (__bf16)(a[3]*s);
    r[4] = (__bf16)(b[0]*s); r[5] = (__bf16)(b[1]*s);
    r[6] = (__bf16)(b[2]*s); r[7] = (__bf16)(b[3]*s);
    return r;
}
__device__ __forceinline__ int fkey(int row) {
    return ((row & 7) ^ ((row >> 3) << 1)) & 7;
}

__global__ __launch_bounds__(512, 4)
void sdpa_flash_kernel(const float* __restrict__ q,
                       const float* __restrict__ k,
                       const float* __restrict__ v,
                       const float* __restrict__ mask,
                       float* __restrict__ out)
{
    // sK: [krow][d], key krow&7.  sV: [d][krow] (V^T), key (d^(d>>3))&7.
    // sP: per-wave, double-buffered, [qrow][kcol], key fkey(qrow).
    __shared__ unsigned short sK[2][64 * 64];
    __shared__ unsigned short sV[3][64 * 64];
    __shared__ unsigned short sP[8][2][16 * 64];

    const int tid  = threadIdx.x;
    const int wv   = tid >> 6;
    const int lane = tid & 63;
    const int quad = lane >> 4;
    const int ln   = lane & 15;

    const int fid = blockIdx.x;
    const int bh  = (fid & 7) | ((fid >> 7) << 3);     // XCD-local heads
    const int qb  = ((fid >> 3) & 15) * cQT;
    const int mb  = bh & 1;

    const float L2E = 1.4426950408889634f;

    // ---- Q fragments, pre-scaled by 0.125*log2(e) ----
    bf16x8 aq0, aq1;
    {
        const float* qp = q + ((size_t)bh * cS + qb + wv * 16 + ln) * cD + quad * 8;
        aq0 = pack8s(*(const f32x4*)(qp),      *(const f32x4*)(qp + 4),  0.125f * L2E);
        aq1 = pack8s(*(const f32x4*)(qp + 32), *(const f32x4*)(qp + 36), 0.125f * L2E);
    }

    f32x4 acc[4];
    float lsum[4];
#pragma unroll
    for (int t = 0; t < 4; ++t) acc[t] = (f32x4){0.f, 0.f, 0.f, 0.f};
#pragma unroll
    for (int r = 0; r < 4; ++r) lsum[r] = 0.f;

    // ---- staging geometry (lane-consecutive 16B chunks) ----
    const int srow = tid >> 4;                 // 0..31
    const int col4 = (tid & 15) << 2;
    const int ka0  = srow * 64 + (((col4 >> 3) ^ (srow & 7)) << 3) + (col4 & 7);
    const int ka1  = ka0 + 32 * 64;
    const float* kg = k + (size_t)bh * cS * cD;
    const float* vg = v + (size_t)bh * cS * cD;
    const int g0 = tid * 4, g1 = 2048 + tid * 4;

    // ---- mask row pointers (advanced 64 floats / tile) ----
    const float* mr0 = mask + (size_t)mb * cS * cS
                            + (size_t)(qb + wv * 16 + quad * 4) * cS + ln;
    const float* mr1 = mr0 + cS;
    const float* mr2 = mr0 + 2 * cS;
    const float* mr3 = mr0 + 3 * cS;

    // ---- preload + stage tile 0; mask(0) into mc ----
    {
        f32x4 K0 = *(const f32x4*)(kg + g0);
        f32x4 K1 = *(const f32x4*)(kg + g1);
        f32x4 V0 = *(const f32x4*)(vg + g0);
        f32x4 V1 = *(const f32x4*)(vg + g1);
        *(bf16x4*)&sK[0][ka0] = pack4(K0);
        *(bf16x4*)&sK[0][ka1] = pack4(K1);
#pragma unroll
        for (int j = 0; j < 4; ++j) {
            int d = col4 + j, g = (d ^ (d >> 3)) & 7;
            sV[0][d * 64 + (((srow >> 3) ^ g) << 3) + (srow & 7)]       = bfbits(V0[j]);
            sV[0][d * 64 + ((((srow >> 3) + 4) ^ g) << 3) + (srow & 7)] = bfbits(V1[j]);
        }
    }
    float mc[16];
#pragma unroll
    for (int nt = 0; nt < 4; ++nt) {
        mc[nt * 4 + 0] = mr0[nt * 16]; mc[nt * 4 + 1] = mr1[nt * 16];
        mc[nt * 4 + 2] = mr2[nt * 16]; mc[nt * 4 + 3] = mr3[nt * 16];
    }
    mr0 += 64; mr1 += 64; mr2 += 64; mr3 += 64;

    int vprv = 2, vcur = 0, vnxt = 1;          // V ring: vcur == kt % 3

    for (int kt = 0; kt < cNT; ++kt) {
        const int kcur = kt & 1;

        // prefetch K/V(kt+1) and mask(kt+1) into registers
        f32x4 K0, K1, V0, V1;
        float mn[16];
        if (kt + 1 < cNT) {
            const int tb = (kt + 1) * 4096;
            K0 = *(const f32x4*)(kg + tb + g0);
            K1 = *(const f32x4*)(kg + tb + g1);
            V0 = *(const f32x4*)(vg + tb + g0);
            V1 = *(const f32x4*)(vg + tb + g1);
#pragma unroll
            for (int nt = 0; nt < 4; ++nt) {
                mn[nt * 4 + 0] = mr0[nt * 16]; mn[nt * 4 + 1] = mr1[nt * 16];
                mn[nt * 4 + 2] = mr2[nt * 16]; mn[nt * 4 + 3] = mr3[nt * 16];
            }
            mr0 += 64; mr1 += 64; mr2 += 64; mr3 += 64;
        }

        __syncthreads();   // sK[kcur], sV[vcur] staged; sP[t-1] per-wave ordered

        // ---- QK(t): P = exp2(c + mask*l2e), write sP[wv][kcur] ----
        const unsigned short* sKc = sK[kcur];
        unsigned short* sPw = &sP[wv][kcur][0];
        float p4[4][4];
#pragma unroll
        for (int nt = 0; nt < 4; ++nt) {
            f32x4 c = (f32x4){0.f, 0.f, 0.f, 0.f};
#pragma unroll
            for (int ks = 0; ks < 2; ++ks) {
                bf16x8 b = *(const bf16x8*)(
                    &sKc[(nt * 16 + ln) * 64 + ((((ks << 2) | quad) ^ (ln & 7)) << 3)]);
                c = __builtin_amdgcn_mfma_f32_16x16x32_bf16(ks ? aq1 : aq0, b, c, 0, 0, 0);
            }
#pragma unroll
            for (int r = 0; r < 4; ++r)
                p4[nt][r] = __builtin_amdgcn_exp2f(fmaf(mc[nt * 4 + r], L2E, c[r]));
        }
#pragma unroll
        for (int r = 0; r < 4; ++r)
            lsum[r] += (p4[0][r] + p4[1][r]) + (p4[2][r] + p4[3][r]);
#pragma unroll
        for (int nt = 0; nt < 4; ++nt)
#pragma unroll
            for (int r = 0; r < 4; ++r) {
                int row = quad * 4 + r;
                int blk = ((nt * 2 + (ln >> 3)) ^ fkey(row)) << 3;
                sPw[row * 64 + blk + (ln & 7)] = bfbits(p4[nt][r]);
            }

        // ---- PV(t-1): sP[wv][kcur^1] x sV[vprv]  (independent MFMA stream) ----
        if (kt > 0) {
            const unsigned short* sPr = &sP[wv][kcur ^ 1][0];
            const unsigned short* sVp = sV[vprv];
#pragma unroll
            for (int ks = 0; ks < 2; ++ks) {
                bf16x8 ap = *(const bf16x8*)(
                    &sPr[ln * 64 + ((((ks << 2) | quad) ^ fkey(ln)) << 3)]);
#pragma unroll
                for (int dt = 0; dt < 4; ++dt) {
                    int d = dt * 16 + ln, g = (d ^ (d >> 3)) & 7;
                    bf16x8 bv = *(const bf16x8*)(
                        &sVp[d * 64 + ((((ks << 2) | quad) ^ g) << 3)]);
                    acc[dt] = __builtin_amdgcn_mfma_f32_16x16x32_bf16(ap, bv, acc[dt], 0, 0, 0);
                }
            }
        }

        // ---- stage tile t+1: sK[kcur^1], sV[vnxt] ----
        // safe: sK[kcur^1] last read by QK(t-1) before top-of-t barrier;
        // sV[vnxt] == sV[(t+1)%3], readers of it (PV(t-2)) finished pre-barrier.
        if (kt + 1 < cNT) {
            unsigned short* sKn = sK[kcur ^ 1];
            unsigned short* sVn = sV[vnxt];
            *(bf16x4*)&sKn[ka0] = pack4(K0);
            *(bf16x4*)&sKn[ka1] = pack4(K1);
#pragma unroll
            for (int j = 0; j < 4; ++j) {
                int d = col4 + j, g = (d ^ (d >> 3)) & 7;
                sVn[d * 64 + (((srow >> 3) ^ g) << 3) + (srow & 7)]       = bfbits(V0[j]);
                sVn[d * 64 + ((((srow >> 3) + 4) ^ g) << 3) + (srow & 7)] = bfbits(V1[j]);
            }
#pragma unroll
            for (int i = 0; i < 16; ++i) mc[i] = mn[i];
        }

        int t = vprv; vprv = vcur; vcur = vnxt; vnxt = t;   // rotate 3-ring
    }

    // ---- drain: PV(cNT-1) from sP[wv][1], sV[vprv] ----
    {
        const unsigned short* sPr = &sP[wv][(cNT - 1) & 1][0];
        const unsigned short* sVp = sV[vprv];
#pragma unroll
        for (int ks = 0; ks < 2; ++ks) {
            bf16x8 ap = *(const bf16x8*)(
                &sPr[ln * 64 + ((((ks << 2) | quad) ^ fkey(ln)) << 3)]);
#pragma unroll
            for (int dt = 0; dt < 4; ++dt) {
                int d = dt * 16 + ln, g = (d ^ (d >> 3)) & 7;
                bf16x8 bv = *(const bf16x8*)(
                    &sVp[d * 64 + ((((ks << 2) | quad) ^ g) << 3)]);
                acc[dt] = __builtin_amdgcn_mfma_f32_16x16x32_bf16(ap, bv, acc[dt], 0, 0, 0);
            }
        }
    }

    // ---- epilogue: row-sum reduce, O = acc / l ----
#pragma unroll
    for (int off = 1; off < 16; off <<= 1)
#pragma unroll
        for (int r = 0; r < 4; ++r)
            lsum[r] += __shfl_xor(lsum[r], off, 64);
    float rl[4];
#pragma unroll
    for (int r = 0; r < 4; ++r) rl[r] = 1.0f / lsum[r];
#pragma unroll
    for (int dt = 0; dt < 4; ++dt)
#pragma unroll
        for (int r = 0; r < 4; ++r)
            out[((size_t)bh * cS + qb + wv * 16 + quad * 4 + r) * cD + dt * 16 + ln]
                = acc[dt][r] * rl[r];
}

extern "C" void kernel_launch(void* const* d_in, const int* in_sizes, int n_in,
                              void* d_out, int out_size, void* d_ws, size_t ws_size,
                              hipStream_t stream) {
    const float* q = (const float*)d_in[0];
    const float* k = (const float*)d_in[1];
    const float* v = (const float*)d_in[2];
    const float* m = (const float*)d_in[3];
    float* o = (float*)d_out;
    sdpa_flash_kernel<<<dim3(512), 512, 0, stream>>>(q, k, v, m, o);
}

// Round 6
// 208.009 us; speedup vs baseline: 1.4485x; 1.4485x over previous
//
#include <hip/hip_runtime.h>

// Flash attention fwd: fp32 I/O, bf16 MFMA, fp32 softmax math.
// BH=32, S=2048, D=64, additive mask [2,S,S] tiled bh%2.
// R6: R5 pipeline (PV deferred one tile, sP dbuf, sV 3-ring, mask prefetch)
// with the register cap released: __launch_bounds__(512,2) -> >=128 VGPR/wave.
// (512,4) had CUDA blocks/CU semantics -> 8 waves/SIMD -> 64-VGPR cap -> spills
// (WRITE_SIZE 61MB vs 16MB ideal). LDS=72KB pins 2 blocks/CU anyway.

constexpr int cBH = 32;
constexpr int cS  = 2048;
constexpr int cD  = 64;
constexpr int cQT = 128;            // 8 waves x 16 q-rows
constexpr int cNT = cS / 64;        // 32 k-tiles

typedef __bf16 bf16x8 __attribute__((ext_vector_type(8)));
typedef __bf16 bf16x4 __attribute__((ext_vector_type(4)));
typedef float  f32x4  __attribute__((ext_vector_type(4)));

__device__ __forceinline__ unsigned short bfbits(float f) {
    return __builtin_bit_cast(unsigned short, (__bf16)f);
}
__device__ __forceinline__ bf16x4 pack4(f32x4 a) {
    bf16x4 r;
    r[0] = (__bf16)a[0]; r[1] = (__bf16)a[1];
    r[2] = (__bf16)a[2]; r[3] = (__bf16)a[3];
    return r;
}
__device__ __forceinline__ bf16x8 pack8s(f32x4 a, f32x4 b, float s) {
    bf16x8 r;
    r[0] = (__bf16)(a[0]*s); r[1] = (__bf16)(a[1]*s);
    r[2] = (__bf16)(a[2]*s); r[3] = (__bf16)(a[3]*s);
    r[4] = (__bf16)(b[0]*s); r[5] = (__bf16)(b[1]*s);
    r[6] = (__bf16)(b[2]*s); r[7] = (__bf16)(b[3]*s);
    return r;
}
__device__ __forceinline__ int fkey(int row) {
    return ((row & 7) ^ ((row >> 3) << 1)) & 7;
}

__global__ __launch_bounds__(512, 2)
void sdpa_flash_kernel(const float* __restrict__ q,
                       const float* __restrict__ k,
                       const float* __restrict__ v,
                       const float* __restrict__ mask,
                       float* __restrict__ out)
{
    // sK: [krow][d], key krow&7.  sV: [d][krow] (V^T), key (d^(d>>3))&7.
    // sP: per-wave, double-buffered, [qrow][kcol], key fkey(qrow).
    __shared__ unsigned short sK[2][64 * 64];
    __shared__ unsigned short sV[3][64 * 64];
    __shared__ unsigned short sP[8][2][16 * 64];

    const int tid  = threadIdx.x;
    const int wv   = tid >> 6;
    const int lane = tid & 63;
    const int quad = lane >> 4;
    const int ln   = lane & 15;

    const int fid = blockIdx.x;
    const int bh  = (fid & 7) | ((fid >> 7) << 3);     // XCD-local heads
    const int qb  = ((fid >> 3) & 15) * cQT;
    const int mb  = bh & 1;

    const float L2E = 1.4426950408889634f;

    // ---- Q fragments, pre-scaled by 0.125*log2(e) ----
    bf16x8 aq0, aq1;
    {
        const float* qp = q + ((size_t)bh * cS + qb + wv * 16 + ln) * cD + quad * 8;
        aq0 = pack8s(*(const f32x4*)(qp),      *(const f32x4*)(qp + 4),  0.125f * L2E);
        aq1 = pack8s(*(const f32x4*)(qp + 32), *(const f32x4*)(qp + 36), 0.125f * L2E);
    }

    f32x4 acc[4];
    float lsum[4];
#pragma unroll
    for (int t = 0; t < 4; ++t) acc[t] = (f32x4){0.f, 0.f, 0.f, 0.f};
#pragma unroll
    for (int r = 0; r < 4; ++r) lsum[r] = 0.f;

    // ---- staging geometry (lane-consecutive 16B chunks) ----
    const int srow = tid >> 4;                 // 0..31
    const int col4 = (tid & 15) << 2;
    const int ka0  = srow * 64 + (((col4 >> 3) ^ (srow & 7)) << 3) + (col4 & 7);
    const int ka1  = ka0 + 32 * 64;
    const float* kg = k + (size_t)bh * cS * cD;
    const float* vg = v + (size_t)bh * cS * cD;
    const int g0 = tid * 4, g1 = 2048 + tid * 4;

    // ---- mask row pointers (advanced 64 floats / tile) ----
    const float* mr0 = mask + (size_t)mb * cS * cS
                            + (size_t)(qb + wv * 16 + quad * 4) * cS + ln;
    const float* mr1 = mr0 + cS;
    const float* mr2 = mr0 + 2 * cS;
    const float* mr3 = mr0 + 3 * cS;

    // ---- preload + stage tile 0; mask(0) into mc ----
    {
        f32x4 K0 = *(const f32x4*)(kg + g0);
        f32x4 K1 = *(const f32x4*)(kg + g1);
        f32x4 V0 = *(const f32x4*)(vg + g0);
        f32x4 V1 = *(const f32x4*)(vg + g1);
        *(bf16x4*)&sK[0][ka0] = pack4(K0);
        *(bf16x4*)&sK[0][ka1] = pack4(K1);
#pragma unroll
        for (int j = 0; j < 4; ++j) {
            int d = col4 + j, g = (d ^ (d >> 3)) & 7;
            sV[0][d * 64 + (((srow >> 3) ^ g) << 3) + (srow & 7)]       = bfbits(V0[j]);
            sV[0][d * 64 + ((((srow >> 3) + 4) ^ g) << 3) + (srow & 7)] = bfbits(V1[j]);
        }
    }
    float mc[16];
#pragma unroll
    for (int nt = 0; nt < 4; ++nt) {
        mc[nt * 4 + 0] = mr0[nt * 16]; mc[nt * 4 + 1] = mr1[nt * 16];
        mc[nt * 4 + 2] = mr2[nt * 16]; mc[nt * 4 + 3] = mr3[nt * 16];
    }

    int vprv = 2, vcur = 0, vnxt = 1;          // V ring: vcur == kt % 3

    for (int kt = 0; kt < cNT; ++kt) {
        const int kcur = kt & 1;
        const bool more = (kt + 1 < cNT);
        // clamped so loads are unconditional (better scheduling, no exec mask)
        const int tnx = more ? kt + 1 : kt;

        // prefetch K/V(t+1) and mask(t+1) into registers
        const int tb = tnx * 4096;
        f32x4 K0 = *(const f32x4*)(kg + tb + g0);
        f32x4 K1 = *(const f32x4*)(kg + tb + g1);
        f32x4 V0 = *(const f32x4*)(vg + tb + g0);
        f32x4 V1 = *(const f32x4*)(vg + tb + g1);
        float mn[16];
        {
            const int mo = tnx * 64;
#pragma unroll
            for (int nt = 0; nt < 4; ++nt) {
                mn[nt * 4 + 0] = mr0[mo + nt * 16]; mn[nt * 4 + 1] = mr1[mo + nt * 16];
                mn[nt * 4 + 2] = mr2[mo + nt * 16]; mn[nt * 4 + 3] = mr3[mo + nt * 16];
            }
        }

        __syncthreads();   // sK[kcur], sV[vcur] staged

        // ---- QK(t): P = exp2(c + mask*l2e), write sP[wv][kcur] ----
        const unsigned short* sKc = sK[kcur];
        unsigned short* sPw = &sP[wv][kcur][0];
        float p4[4][4];
#pragma unroll
        for (int nt = 0; nt < 4; ++nt) {
            f32x4 c = (f32x4){0.f, 0.f, 0.f, 0.f};
#pragma unroll
            for (int ks = 0; ks < 2; ++ks) {
                bf16x8 b = *(const bf16x8*)(
                    &sKc[(nt * 16 + ln) * 64 + ((((ks << 2) | quad) ^ (ln & 7)) << 3)]);
                c = __builtin_amdgcn_mfma_f32_16x16x32_bf16(ks ? aq1 : aq0, b, c, 0, 0, 0);
            }
#pragma unroll
            for (int r = 0; r < 4; ++r)
                p4[nt][r] = __builtin_amdgcn_exp2f(fmaf(mc[nt * 4 + r], L2E, c[r]));
        }
#pragma unroll
        for (int r = 0; r < 4; ++r)
            lsum[r] += (p4[0][r] + p4[1][r]) + (p4[2][r] + p4[3][r]);
#pragma unroll
        for (int nt = 0; nt < 4; ++nt)
#pragma unroll
            for (int r = 0; r < 4; ++r) {
                int row = quad * 4 + r;
                int blk = ((nt * 2 + (ln >> 3)) ^ fkey(row)) << 3;
                sPw[row * 64 + blk + (ln & 7)] = bfbits(p4[nt][r]);
            }

        // ---- PV(t-1): sP[wv][kcur^1] x sV[vprv]  (independent MFMA stream) ----
        if (kt > 0) {
            const unsigned short* sPr = &sP[wv][kcur ^ 1][0];
            const unsigned short* sVp = sV[vprv];
#pragma unroll
            for (int ks = 0; ks < 2; ++ks) {
                bf16x8 ap = *(const bf16x8*)(
                    &sPr[ln * 64 + ((((ks << 2) | quad) ^ fkey(ln)) << 3)]);
#pragma unroll
                for (int dt = 0; dt < 4; ++dt) {
                    int d = dt * 16 + ln, g = (d ^ (d >> 3)) & 7;
                    bf16x8 bv = *(const bf16x8*)(
                        &sVp[d * 64 + ((((ks << 2) | quad) ^ g) << 3)]);
                    acc[dt] = __builtin_amdgcn_mfma_f32_16x16x32_bf16(ap, bv, acc[dt], 0, 0, 0);
                }
            }
        }

        // ---- stage tile t+1: sK[kcur^1], sV[vnxt] ----
        // sK[kcur^1]: last read by QK(t-1), all waves passed top-of-t barrier.
        // sV[vnxt]=(t+1)%3: its readers (PV(t-2)) finished before that barrier.
        if (more) {
            unsigned short* sKn = sK[kcur ^ 1];
            unsigned short* sVn = sV[vnxt];
            *(bf16x4*)&sKn[ka0] = pack4(K0);
            *(bf16x4*)&sKn[ka1] = pack4(K1);
#pragma unroll
            for (int j = 0; j < 4; ++j) {
                int d = col4 + j, g = (d ^ (d >> 3)) & 7;
                sVn[d * 64 + (((srow >> 3) ^ g) << 3) + (srow & 7)]       = bfbits(V0[j]);
                sVn[d * 64 + ((((srow >> 3) + 4) ^ g) << 3) + (srow & 7)] = bfbits(V1[j]);
            }
        }
#pragma unroll
        for (int i = 0; i < 16; ++i) mc[i] = mn[i];

        int t = vprv; vprv = vcur; vcur = vnxt; vnxt = t;   // rotate 3-ring
    }

    // ---- drain: PV(cNT-1) from sP[wv][(cNT-1)&1], sV[vprv] ----
    {
        const unsigned short* sPr = &sP[wv][(cNT - 1) & 1][0];
        const unsigned short* sVp = sV[vprv];
#pragma unroll
        for (int ks = 0; ks < 2; ++ks) {
            bf16x8 ap = *(const bf16x8*)(
                &sPr[ln * 64 + ((((ks << 2) | quad) ^ fkey(ln)) << 3)]);
#pragma unroll
            for (int dt = 0; dt < 4; ++dt) {
                int d = dt * 16 + ln, g = (d ^ (d >> 3)) & 7;
                bf16x8 bv = *(const bf16x8*)(
                    &sVp[d * 64 + ((((ks << 2) | quad) ^ g) << 3)]);
                acc[dt] = __builtin_amdgcn_mfma_f32_16x16x32_bf16(ap, bv, acc[dt], 0, 0, 0);
            }
        }
    }

    // ---- epilogue: row-sum reduce, O = acc / l ----
#pragma unroll
    for (int off = 1; off < 16; off <<= 1)
#pragma unroll
        for (int r = 0; r < 4; ++r)
            lsum[r] += __shfl_xor(lsum[r], off, 64);
    float rl[4];
#pragma unroll
    for (int r = 0; r < 4; ++r) rl[r] = 1.0f / lsum[r];
#pragma unroll
    for (int dt = 0; dt < 4; ++dt)
#pragma unroll
        for (int r = 0; r < 4; ++r)
            out[((size_t)bh * cS + qb + wv * 16 + quad * 4 + r) * cD + dt * 16 + ln]
                = acc[dt][r] * rl[r];
}

extern "C" void kernel_launch(void* const* d_in, const int* in_sizes, int n_in,
                              void* d_out, int out_size, void* d_ws, size_t ws_size,
                              hipStream_t stream) {
    const float* q = (const float*)d_in[0];
    const float* k = (const float*)d_in[1];
    const float* v = (const float*)d_in[2];
    const float* m = (const float*)d_in[3];
    float* o = (float*)d_out;
    sdpa_flash_kernel<<<dim3(512), 512, 0, stream>>>(q, k, v, m, o);
}

// Round 7
// 178.696 us; speedup vs baseline: 1.6861x; 1.1640x over previous
//
#include <hip/hip_runtime.h>

// Flash attention fwd: fp32 I/O, bf16 MFMA, fp32 softmax math.
// BH=32, S=2048, D=64, additive mask [2,S,S] tiled bh%2.
// R7: m-tiled waves — each wave computes 32 q-rows (2 m-groups of 16) so every
// K/V B-fragment LDS read is reused by 2 MFMAs. 4 waves/block, 256 threads,
// 128 q-rows/block, K/V dbuf (48 KB LDS), same-tile PV, single barrier/tile,
// reg-prefetched K/V/mask. (256,2): cap 256 VGPR, no spill at ~200.

constexpr int cBH = 32;
constexpr int cS  = 2048;
constexpr int cD  = 64;
constexpr int cQT = 128;            // 4 waves x 32 q-rows
constexpr int cNT = cS / 64;        // 32 k-tiles

typedef __bf16 bf16x8 __attribute__((ext_vector_type(8)));
typedef __bf16 bf16x4 __attribute__((ext_vector_type(4)));
typedef float  f32x4  __attribute__((ext_vector_type(4)));

__device__ __forceinline__ unsigned short bfbits(float f) {
    return __builtin_bit_cast(unsigned short, (__bf16)f);
}
__device__ __forceinline__ bf16x4 pack4(f32x4 a) {
    bf16x4 r;
    r[0] = (__bf16)a[0]; r[1] = (__bf16)a[1];
    r[2] = (__bf16)a[2]; r[3] = (__bf16)a[3];
    return r;
}
__device__ __forceinline__ bf16x8 pack8s(f32x4 a, f32x4 b, float s) {
    bf16x8 r;
    r[0] = (__bf16)(a[0]*s); r[1] = (__bf16)(a[1]*s);
    r[2] = (__bf16)(a[2]*s); r[3] = (__bf16)(a[3]*s);
    r[4] = (__bf16)(b[0]*s); r[5] = (__bf16)(b[1]*s);
    r[6] = (__bf16)(b[2]*s); r[7] = (__bf16)(b[3]*s);
    return r;
}
__device__ __forceinline__ int fkey(int row) {   // sP swizzle key, rows 0..31
    return ((row & 7) ^ ((row >> 3) << 1)) & 7;
}
__device__ __forceinline__ int gkey(int d) {     // sV swizzle key
    return (d ^ (d >> 3)) & 7;
}

__global__ __launch_bounds__(256, 2)
void sdpa_flash_kernel(const float* __restrict__ q,
                       const float* __restrict__ k,
                       const float* __restrict__ v,
                       const float* __restrict__ mask,
                       float* __restrict__ out)
{
    // sK: [krow][d], key krow&7.  sV: [d][krow] (V^T), key gkey(d).
    // sP: per-wave [qrow 0..31][kcol], key fkey(qrow).
    __shared__ unsigned short sK[2][64 * 64];
    __shared__ unsigned short sV[2][64 * 64];
    __shared__ unsigned short sP[4][32 * 64];

    const int tid  = threadIdx.x;
    const int wv   = tid >> 6;
    const int lane = tid & 63;
    const int quad = lane >> 4;
    const int ln   = lane & 15;

    const int fid = blockIdx.x;
    const int bh  = (fid & 7) | ((fid >> 7) << 3);     // XCD-local heads
    const int qb  = ((fid >> 3) & 15) * cQT;
    const int mb  = bh & 1;

    const float L2E = 1.4426950408889634f;

    // ---- Q fragments, pre-scaled by 0.125*log2(e): aq[mg][ks] ----
    bf16x8 aq[2][2];
#pragma unroll
    for (int mg = 0; mg < 2; ++mg) {
        const float* qp = q + ((size_t)bh * cS + qb + wv * 32 + mg * 16 + ln) * cD + quad * 8;
        aq[mg][0] = pack8s(*(const f32x4*)(qp),      *(const f32x4*)(qp + 4),  0.125f * L2E);
        aq[mg][1] = pack8s(*(const f32x4*)(qp + 32), *(const f32x4*)(qp + 36), 0.125f * L2E);
    }

    f32x4 acc[2][4];
    float lsum[2][4];
#pragma unroll
    for (int mg = 0; mg < 2; ++mg)
#pragma unroll
        for (int t = 0; t < 4; ++t) {
            acc[mg][t] = (f32x4){0.f, 0.f, 0.f, 0.f};
            lsum[mg][t] = 0.f;
        }

    // ---- staging geometry: 256 threads, chunk j covers floats j*1024+tid*4 ----
    // srow_j = j*16 + sr0, cols c4..c4+3;  sr0 = tid>>4 (0..15), c4 = (tid&15)*4
    const int sr0 = tid >> 4;
    const int c4  = (tid & 15) << 2;
    const int ka0 = sr0 * 64 + (((c4 >> 3) ^ (sr0 & 7)) << 3) + (c4 & 7);
    const float* kg = k + (size_t)bh * cS * cD;
    const float* vg = v + (size_t)bh * cS * cD;

    // mask base: rows qb+wv*32+quad*4 (+mg*16+r), col ln (+kt*64+nt*16)
    const float* mq = mask + (size_t)mb * cS * cS
                           + (size_t)(qb + wv * 32 + quad * 4) * cS + ln;

    // ---- stage tile 0 directly; load mask(0) ----
#pragma unroll
    for (int j = 0; j < 4; ++j) {
        f32x4 kj = *(const f32x4*)(kg + j * 1024 + tid * 4);
        f32x4 vj = *(const f32x4*)(vg + j * 1024 + tid * 4);
        *(bf16x4*)&sK[0][ka0 + j * 1024] = pack4(kj);
#pragma unroll
        for (int i = 0; i < 4; ++i) {
            int d = c4 + i;
            sV[0][d * 64 + ((((j * 2) + (sr0 >> 3)) ^ gkey(d)) << 3) + (sr0 & 7)]
                = bfbits(vj[i]);
        }
    }
    float mc[2][4][4];
#pragma unroll
    for (int mg = 0; mg < 2; ++mg)
#pragma unroll
        for (int nt = 0; nt < 4; ++nt)
#pragma unroll
            for (int r = 0; r < 4; ++r)
                mc[mg][nt][r] = mq[(size_t)(mg * 16 + r) * cS + nt * 16];

    for (int kt = 0; kt < cNT; ++kt) {
        const int cur = kt & 1;
        const bool more = (kt + 1 < cNT);
        const int tnx = more ? kt + 1 : kt;     // clamped: unconditional loads

        // ---- prefetch K/V(t+1) + mask(t+1) into registers ----
        f32x4 KP[4], VP[4];
        const int tb = tnx * 4096;
#pragma unroll
        for (int j = 0; j < 4; ++j) {
            KP[j] = *(const f32x4*)(kg + tb + j * 1024 + tid * 4);
            VP[j] = *(const f32x4*)(vg + tb + j * 1024 + tid * 4);
        }
        float mn[2][4][4];
#pragma unroll
        for (int mg = 0; mg < 2; ++mg)
#pragma unroll
            for (int nt = 0; nt < 4; ++nt)
#pragma unroll
                for (int r = 0; r < 4; ++r)
                    mn[mg][nt][r] = mq[(size_t)(mg * 16 + r) * cS + tnx * 64 + nt * 16];

        __syncthreads();                        // sK/sV[cur] staged

        // ---- QK: both m-groups share every B-fragment ----
        const unsigned short* sKc = sK[cur];
        float p4[2][4][4];
#pragma unroll
        for (int nt = 0; nt < 4; ++nt) {
            bf16x8 b0 = *(const bf16x8*)(
                &sKc[(nt * 16 + ln) * 64 + ((quad ^ (ln & 7)) << 3)]);
            bf16x8 b1 = *(const bf16x8*)(
                &sKc[(nt * 16 + ln) * 64 + (((4 | quad) ^ (ln & 7)) << 3)]);
            f32x4 c0 = (f32x4){0.f, 0.f, 0.f, 0.f};
            f32x4 c1 = (f32x4){0.f, 0.f, 0.f, 0.f};
            c0 = __builtin_amdgcn_mfma_f32_16x16x32_bf16(aq[0][0], b0, c0, 0, 0, 0);
            c1 = __builtin_amdgcn_mfma_f32_16x16x32_bf16(aq[1][0], b0, c1, 0, 0, 0);
            c0 = __builtin_amdgcn_mfma_f32_16x16x32_bf16(aq[0][1], b1, c0, 0, 0, 0);
            c1 = __builtin_amdgcn_mfma_f32_16x16x32_bf16(aq[1][1], b1, c1, 0, 0, 0);
#pragma unroll
            for (int r = 0; r < 4; ++r) {
                p4[0][nt][r] = __builtin_amdgcn_exp2f(fmaf(mc[0][nt][r], L2E, c0[r]));
                p4[1][nt][r] = __builtin_amdgcn_exp2f(fmaf(mc[1][nt][r], L2E, c1[r]));
            }
        }
#pragma unroll
        for (int mg = 0; mg < 2; ++mg)
#pragma unroll
            for (int r = 0; r < 4; ++r)
                lsum[mg][r] += (p4[mg][0][r] + p4[mg][1][r])
                             + (p4[mg][2][r] + p4[mg][3][r]);

        // ---- P -> per-wave LDS (C-layout -> A-layout), swizzled ----
#pragma unroll
        for (int mg = 0; mg < 2; ++mg)
#pragma unroll
            for (int nt = 0; nt < 4; ++nt)
#pragma unroll
                for (int r = 0; r < 4; ++r) {
                    int row = mg * 16 + quad * 4 + r;
                    int blk = ((nt * 2 + (ln >> 3)) ^ fkey(row)) << 3;
                    sP[wv][row * 64 + blk + (ln & 7)] = bfbits(p4[mg][nt][r]);
                }
        // same-wave DS ordering: no barrier needed before re-reading sP

        // ---- O += P V: V fragments shared by both m-groups ----
        const unsigned short* sVc = sV[cur];
#pragma unroll
        for (int ks = 0; ks < 2; ++ks) {
            bf16x8 ap0 = *(const bf16x8*)(
                &sP[wv][ln * 64 + ((((ks << 2) | quad) ^ fkey(ln)) << 3)]);
            bf16x8 ap1 = *(const bf16x8*)(
                &sP[wv][(16 + ln) * 64 + ((((ks << 2) | quad) ^ fkey(16 + ln)) << 3)]);
#pragma unroll
            for (int dt = 0; dt < 4; ++dt) {
                int d = dt * 16 + ln;
                bf16x8 bv = *(const bf16x8*)(
                    &sVc[d * 64 + ((((ks << 2) | quad) ^ gkey(d)) << 3)]);
                acc[0][dt] = __builtin_amdgcn_mfma_f32_16x16x32_bf16(ap0, bv, acc[0][dt], 0, 0, 0);
                acc[1][dt] = __builtin_amdgcn_mfma_f32_16x16x32_bf16(ap1, bv, acc[1][dt], 0, 0, 0);
            }
        }

        // ---- stage prefetched tile into other buffer ----
        // safe: its readers (tile t-1) finished before this tile's barrier
        if (more) {
            unsigned short* sKn = sK[cur ^ 1];
            unsigned short* sVn = sV[cur ^ 1];
#pragma unroll
            for (int j = 0; j < 4; ++j) {
                *(bf16x4*)&sKn[ka0 + j * 1024] = pack4(KP[j]);
#pragma unroll
                for (int i = 0; i < 4; ++i) {
                    int d = c4 + i;
                    sVn[d * 64 + ((((j * 2) + (sr0 >> 3)) ^ gkey(d)) << 3) + (sr0 & 7)]
                        = bfbits(VP[j][i]);
                }
            }
        }
#pragma unroll
        for (int mg = 0; mg < 2; ++mg)
#pragma unroll
            for (int nt = 0; nt < 4; ++nt)
#pragma unroll
                for (int r = 0; r < 4; ++r)
                    mc[mg][nt][r] = mn[mg][nt][r];
    }

    // ---- epilogue: row-sum reduce, O = acc / l ----
#pragma unroll
    for (int off = 1; off < 16; off <<= 1)
#pragma unroll
        for (int mg = 0; mg < 2; ++mg)
#pragma unroll
            for (int r = 0; r < 4; ++r)
                lsum[mg][r] += __shfl_xor(lsum[mg][r], off, 64);
#pragma unroll
    for (int mg = 0; mg < 2; ++mg) {
        float rl[4];
#pragma unroll
        for (int r = 0; r < 4; ++r) rl[r] = 1.0f / lsum[mg][r];
#pragma unroll
        for (int dt = 0; dt < 4; ++dt)
#pragma unroll
            for (int r = 0; r < 4; ++r)
                out[((size_t)bh * cS + qb + wv * 32 + mg * 16 + quad * 4 + r) * cD
                    + dt * 16 + ln] = acc[mg][dt][r] * rl[r];
    }
}

extern "C" void kernel_launch(void* const* d_in, const int* in_sizes, int n_in,
                              void* d_out, int out_size, void* d_ws, size_t ws_size,
                              hipStream_t stream) {
    const float* q = (const float*)d_in[0];
    const float* k = (const float*)d_in[1];
    const float* v = (const float*)d_in[2];
    const float* m = (const float*)d_in[3];
    float* o = (float*)d_out;
    sdpa_flash_kernel<<<dim3(512), 256, 0, stream>>>(q, k, v, m, o);
}

// Round 8
// 175.438 us; speedup vs baseline: 1.7174x; 1.0186x over previous
//
#include <hip/hip_runtime.h>

// Flash attention fwd: fp32 I/O, bf16 MFMA, fp32 softmax math.
// BH=32, S=2048, D=64, additive mask [2,S,S] tiled bh%2.
// R8: paired k-tiles per iteration — each wave runs 2 independent QK->exp->PV
// chains (x2 m-groups = 4 indep MFMA chains) to cover latency with ILP, since
// occupancy is grid-capped at 8 waves/CU. LDS 64 KB: sK/sV hold the pair,
// next pair register-prefetched; 2 barriers/pair (same rate as R7).

constexpr int cBH = 32;
constexpr int cS  = 2048;
constexpr int cD  = 64;
constexpr int cQT = 128;            // 4 waves x 32 q-rows
constexpr int cNP = cS / 128;       // 16 pairs of 64-wide k-tiles

typedef __bf16 bf16x8 __attribute__((ext_vector_type(8)));
typedef __bf16 bf16x4 __attribute__((ext_vector_type(4)));
typedef float  f32x4  __attribute__((ext_vector_type(4)));

__device__ __forceinline__ unsigned short bfbits(float f) {
    return __builtin_bit_cast(unsigned short, (__bf16)f);
}
__device__ __forceinline__ bf16x4 pack4(f32x4 a) {
    bf16x4 r;
    r[0] = (__bf16)a[0]; r[1] = (__bf16)a[1];
    r[2] = (__bf16)a[2]; r[3] = (__bf16)a[3];
    return r;
}
__device__ __forceinline__ bf16x8 pack8s(f32x4 a, f32x4 b, float s) {
    bf16x8 r;
    r[0] = (__bf16)(a[0]*s); r[1] = (__bf16)(a[1]*s);
    r[2] = (__bf16)(a[2]*s); r[3] = (__bf16)(a[3]*s);
    r[4] = (__bf16)(b[0]*s); r[5] = (__bf16)(b[1]*s);
    r[6] = (__bf16)(b[2]*s); r[7] = (__bf16)(b[3]*s);
    return r;
}
__device__ __forceinline__ int fkey(int row) {   // sP swizzle key, rows 0..31
    return ((row & 7) ^ ((row >> 3) << 1)) & 7;
}
__device__ __forceinline__ int gkey(int d) {     // sV swizzle key
    return (d ^ (d >> 3)) & 7;
}

__global__ __launch_bounds__(256, 2)
void sdpa_flash_kernel(const float* __restrict__ q,
                       const float* __restrict__ k,
                       const float* __restrict__ v,
                       const float* __restrict__ mask,
                       float* __restrict__ out)
{
    // sK[t]: [krow][d], key krow&7.  sV[t]: [d][krow] (V^T), key gkey(d).
    // sP[wave][t]: [qrow 0..31][kcol], key fkey(qrow).   t = tile within pair.
    __shared__ unsigned short sK[2][64 * 64];
    __shared__ unsigned short sV[2][64 * 64];
    __shared__ unsigned short sP[4][2][32 * 64];

    const int tid  = threadIdx.x;
    const int wv   = tid >> 6;
    const int lane = tid & 63;
    const int quad = lane >> 4;
    const int ln   = lane & 15;

    const int fid = blockIdx.x;
    const int bh  = (fid & 7) | ((fid >> 7) << 3);     // XCD-local heads
    const int qb  = ((fid >> 3) & 15) * cQT;
    const int mb  = bh & 1;

    const float L2E = 1.4426950408889634f;

    // ---- Q fragments, pre-scaled by 0.125*log2(e): aq[mg][ks] ----
    bf16x8 aq[2][2];
#pragma unroll
    for (int mg = 0; mg < 2; ++mg) {
        const float* qp = q + ((size_t)bh * cS + qb + wv * 32 + mg * 16 + ln) * cD + quad * 8;
        aq[mg][0] = pack8s(*(const f32x4*)(qp),      *(const f32x4*)(qp + 4),  0.125f * L2E);
        aq[mg][1] = pack8s(*(const f32x4*)(qp + 32), *(const f32x4*)(qp + 36), 0.125f * L2E);
    }

    f32x4 acc[2][4];
    float lsum[2][4];
#pragma unroll
    for (int mg = 0; mg < 2; ++mg)
#pragma unroll
        for (int t = 0; t < 4; ++t) {
            acc[mg][t] = (f32x4){0.f, 0.f, 0.f, 0.f};
            lsum[mg][t] = 0.f;
        }

    // ---- staging geometry: 256 threads; chunk j = floats j*1024 + tid*4 ----
    const int sr0 = tid >> 4;                 // 0..15
    const int c4  = (tid & 15) << 2;
    const int ka0 = sr0 * 64 + (((c4 >> 3) ^ (sr0 & 7)) << 3) + (c4 & 7);
    const float* kg = k + (size_t)bh * cS * cD;
    const float* vg = v + (size_t)bh * cS * cD;
    const float* mq = mask + (size_t)mb * cS * cS
                           + (size_t)(qb + wv * 32 + quad * 4) * cS + ln;

    // ---- stage pair 0 (tiles 0 and 1) directly ----
#pragma unroll
    for (int t = 0; t < 2; ++t)
#pragma unroll
        for (int j = 0; j < 4; ++j) {
            f32x4 kj = *(const f32x4*)(kg + t * 4096 + j * 1024 + tid * 4);
            f32x4 vj = *(const f32x4*)(vg + t * 4096 + j * 1024 + tid * 4);
            *(bf16x4*)&sK[t][ka0 + j * 1024] = pack4(kj);
#pragma unroll
            for (int i = 0; i < 4; ++i) {
                int d = c4 + i;
                sV[t][d * 64 + ((((j * 2) + (sr0 >> 3)) ^ gkey(d)) << 3) + (sr0 & 7)]
                    = bfbits(vj[i]);
            }
        }

    for (int pt = 0; pt < cNP; ++pt) {
        const int base = pt * 2;
        const bool more = (pt + 1 < cNP);
        const int nb = more ? base + 2 : base;      // clamped: uncond. loads

        // ---- prefetch next pair K/V into registers ----
        f32x4 KPe[4], VPe[4], KPo[4], VPo[4];
#pragma unroll
        for (int j = 0; j < 4; ++j) {
            KPe[j] = *(const f32x4*)(kg + (size_t)nb * 4096 + j * 1024 + tid * 4);
            VPe[j] = *(const f32x4*)(vg + (size_t)nb * 4096 + j * 1024 + tid * 4);
            KPo[j] = *(const f32x4*)(kg + (size_t)(nb + 1) * 4096 + j * 1024 + tid * 4);
            VPo[j] = *(const f32x4*)(vg + (size_t)(nb + 1) * 4096 + j * 1024 + tid * 4);
        }
        // ---- current pair's mask values (used ~400+ cyc later) ----
        float mcE[2][4][4], mcO[2][4][4];
#pragma unroll
        for (int mg = 0; mg < 2; ++mg)
#pragma unroll
            for (int nt = 0; nt < 4; ++nt)
#pragma unroll
                for (int r = 0; r < 4; ++r) {
                    const float* mrow = mq + (size_t)(mg * 16 + r) * cS + base * 64 + nt * 16;
                    mcE[mg][nt][r] = mrow[0];
                    mcO[mg][nt][r] = mrow[64];
                }

        __syncthreads();                            // pair staged & visible

        // ---- QK both tiles x both m-groups: 4 independent chains ----
        float pE[2][4][4], pO[2][4][4];
#pragma unroll
        for (int nt = 0; nt < 4; ++nt) {
            const int rb = (nt * 16 + ln) * 64;
            const int x0 = (quad ^ (ln & 7)) << 3;
            const int x1 = ((4 | quad) ^ (ln & 7)) << 3;
            bf16x8 be0 = *(const bf16x8*)(&sK[0][rb + x0]);
            bf16x8 be1 = *(const bf16x8*)(&sK[0][rb + x1]);
            bf16x8 bo0 = *(const bf16x8*)(&sK[1][rb + x0]);
            bf16x8 bo1 = *(const bf16x8*)(&sK[1][rb + x1]);
            f32x4 ce0 = (f32x4){0.f,0.f,0.f,0.f}, ce1 = ce0, co0 = ce0, co1 = ce0;
            ce0 = __builtin_amdgcn_mfma_f32_16x16x32_bf16(aq[0][0], be0, ce0, 0, 0, 0);
            ce1 = __builtin_amdgcn_mfma_f32_16x16x32_bf16(aq[1][0], be0, ce1, 0, 0, 0);
            co0 = __builtin_amdgcn_mfma_f32_16x16x32_bf16(aq[0][0], bo0, co0, 0, 0, 0);
            co1 = __builtin_amdgcn_mfma_f32_16x16x32_bf16(aq[1][0], bo0, co1, 0, 0, 0);
            ce0 = __builtin_amdgcn_mfma_f32_16x16x32_bf16(aq[0][1], be1, ce0, 0, 0, 0);
            ce1 = __builtin_amdgcn_mfma_f32_16x16x32_bf16(aq[1][1], be1, ce1, 0, 0, 0);
            co0 = __builtin_amdgcn_mfma_f32_16x16x32_bf16(aq[0][1], bo1, co0, 0, 0, 0);
            co1 = __builtin_amdgcn_mfma_f32_16x16x32_bf16(aq[1][1], bo1, co1, 0, 0, 0);
#pragma unroll
            for (int r = 0; r < 4; ++r) {
                pE[0][nt][r] = __builtin_amdgcn_exp2f(fmaf(mcE[0][nt][r], L2E, ce0[r]));
                pE[1][nt][r] = __builtin_amdgcn_exp2f(fmaf(mcE[1][nt][r], L2E, ce1[r]));
                pO[0][nt][r] = __builtin_amdgcn_exp2f(fmaf(mcO[0][nt][r], L2E, co0[r]));
                pO[1][nt][r] = __builtin_amdgcn_exp2f(fmaf(mcO[1][nt][r], L2E, co1[r]));
            }
        }
#pragma unroll
        for (int mg = 0; mg < 2; ++mg)
#pragma unroll
            for (int r = 0; r < 4; ++r)
                lsum[mg][r] += (pE[mg][0][r] + pE[mg][1][r]) + (pE[mg][2][r] + pE[mg][3][r])
                             + (pO[mg][0][r] + pO[mg][1][r]) + (pO[mg][2][r] + pO[mg][3][r]);

        // ---- P -> per-wave LDS (C -> A layout), both tiles ----
#pragma unroll
        for (int mg = 0; mg < 2; ++mg)
#pragma unroll
            for (int nt = 0; nt < 4; ++nt)
#pragma unroll
                for (int r = 0; r < 4; ++r) {
                    int row = mg * 16 + quad * 4 + r;
                    int blk = ((nt * 2 + (ln >> 3)) ^ fkey(row)) << 3;
                    sP[wv][0][row * 64 + blk + (ln & 7)] = bfbits(pE[mg][nt][r]);
                    sP[wv][1][row * 64 + blk + (ln & 7)] = bfbits(pO[mg][nt][r]);
                }
        // same-wave DS ordering: reads below drain after these writes

        // ---- O += P V, both tiles (8 acc chains interleave) ----
#pragma unroll
        for (int t = 0; t < 2; ++t) {
            const unsigned short* sPt = &sP[wv][t][0];
            const unsigned short* sVt = sV[t];
#pragma unroll
            for (int ks = 0; ks < 2; ++ks) {
                bf16x8 ap0 = *(const bf16x8*)(
                    &sPt[ln * 64 + ((((ks << 2) | quad) ^ fkey(ln)) << 3)]);
                bf16x8 ap1 = *(const bf16x8*)(
                    &sPt[(16 + ln) * 64 + ((((ks << 2) | quad) ^ fkey(16 + ln)) << 3)]);
#pragma unroll
                for (int dt = 0; dt < 4; ++dt) {
                    int d = dt * 16 + ln;
                    bf16x8 bv = *(const bf16x8*)(
                        &sVt[d * 64 + ((((ks << 2) | quad) ^ gkey(d)) << 3)]);
                    acc[0][dt] = __builtin_amdgcn_mfma_f32_16x16x32_bf16(ap0, bv, acc[0][dt], 0, 0, 0);
                    acc[1][dt] = __builtin_amdgcn_mfma_f32_16x16x32_bf16(ap1, bv, acc[1][dt], 0, 0, 0);
                }
            }
        }

        __syncthreads();                            // pair reads complete

        // ---- stage next pair from registers ----
        if (more) {
#pragma unroll
            for (int j = 0; j < 4; ++j) {
                *(bf16x4*)&sK[0][ka0 + j * 1024] = pack4(KPe[j]);
                *(bf16x4*)&sK[1][ka0 + j * 1024] = pack4(KPo[j]);
#pragma unroll
                for (int i = 0; i < 4; ++i) {
                    int d = c4 + i;
                    int va = d * 64 + ((((j * 2) + (sr0 >> 3)) ^ gkey(d)) << 3) + (sr0 & 7);
                    sV[0][va] = bfbits(VPe[j][i]);
                    sV[1][va] = bfbits(VPo[j][i]);
                }
            }
        }
    }

    // ---- epilogue: row-sum reduce, O = acc / l ----
#pragma unroll
    for (int off = 1; off < 16; off <<= 1)
#pragma unroll
        for (int mg = 0; mg < 2; ++mg)
#pragma unroll
            for (int r = 0; r < 4; ++r)
                lsum[mg][r] += __shfl_xor(lsum[mg][r], off, 64);
#pragma unroll
    for (int mg = 0; mg < 2; ++mg) {
        float rl[4];
#pragma unroll
        for (int r = 0; r < 4; ++r) rl[r] = 1.0f / lsum[mg][r];
#pragma unroll
        for (int dt = 0; dt < 4; ++dt)
#pragma unroll
            for (int r = 0; r < 4; ++r)
                out[((size_t)bh * cS + qb + wv * 32 + mg * 16 + quad * 4 + r) * cD
                    + dt * 16 + ln] = acc[mg][dt][r] * rl[r];
    }
}

extern "C" void kernel_launch(void* const* d_in, const int* in_sizes, int n_in,
                              void* d_out, int out_size, void* d_ws, size_t ws_size,
                              hipStream_t stream) {
    const float* q = (const float*)d_in[0];
    const float* k = (const float*)d_in[1];
    const float* v = (const float*)d_in[2];
    const float* m = (const float*)d_in[3];
    float* o = (float*)d_out;
    sdpa_flash_kernel<<<dim3(512), 256, 0, stream>>>(q, k, v, m, o);
}